// Round 1
// baseline (189.968 us; speedup 1.0000x reference)
//
#include <hip/hip_runtime.h>
#include <stdint.h>

#define A_CNT 16320
#define N_TOT (23 * A_CNT)       // 375360
#define G1_END A_CNT             // group0: [0, 16320)   td=16, W=1
#define G2_END (10 * A_CNT)      // group1: [16320,163200) td=8, W=9
#define BATCH 2
#define TOPK 2000
#define CAND_CAP 2048

// ws layout (u32 index / byte offset):
//   u32[0..511]    hist[2][256]
//   u32[512..513]  prefix[2]  (radix-select threshold, built over 4 passes)
//   u32[514..515]  kRemain[2]
//   u32[516..517]  candCount[2]
//   byte 4096      cand[2][CAND_CAP]  u64 packed (key<<32 | ~idx)
//   byte 36864     sorted[2][TOPK]    u64 packed
// total < 70 KB

__device__ __forceinline__ uint32_t fkey(float v) {
  uint32_t u = __float_as_uint(v);
  return (u & 0x80000000u) ? ~u : (u | 0x80000000u);
}

__device__ __forceinline__ uint32_t score_key(int b, int n, const float* s1,
                                              const float* s2, const float* s3) {
  float v;
  if (n < G1_END) {
    v = s1[(b * A_CNT + n) * 2 + 1];
  } else if (n < G2_END) {
    int m = n - G1_END;
    int j = m / A_CNT;
    int a = m - j * A_CNT;
    v = s2[((b * 9 + j) * A_CNT + a) * 2 + 1];
  } else {
    int m = n - G2_END;
    int j = m / A_CNT;
    int a = m - j * A_CNT;
    v = s3[((b * 13 + j) * A_CNT + a) * 2 + 1];
  }
  return fkey(v);
}

__global__ void k_init(uint32_t* ws) {
  int t = blockIdx.x * blockDim.x + threadIdx.x;
  if (t < 512) ws[t] = 0;
  if (t == 0) {
    ws[512] = 0u; ws[513] = 0u;
    ws[514] = TOPK; ws[515] = TOPK;
    ws[516] = 0u; ws[517] = 0u;
  }
}

__global__ void k_hist(const float* __restrict__ s1, const float* __restrict__ s2,
                       const float* __restrict__ s3, uint32_t* ws, int shift) {
  __shared__ uint32_t lh[BATCH * 256];
  for (int i = threadIdx.x; i < BATCH * 256; i += blockDim.x) lh[i] = 0;
  __syncthreads();
  uint32_t maskHi = (shift >= 24) ? 0u : (0xFFFFFFFFu << (shift + 8));
  uint32_t p0 = ws[512] & maskHi;
  uint32_t p1 = ws[513] & maskHi;
  const int total = BATCH * N_TOT;
  for (int idx = blockIdx.x * blockDim.x + threadIdx.x; idx < total;
       idx += gridDim.x * blockDim.x) {
    int b = (idx >= N_TOT) ? 1 : 0;
    int n = idx - b * N_TOT;
    uint32_t key = score_key(b, n, s1, s2, s3);
    uint32_t pref = b ? p1 : p0;
    if ((key & maskHi) == pref)
      atomicAdd(&lh[b * 256 + ((key >> shift) & 255u)], 1u);
  }
  __syncthreads();
  for (int i = threadIdx.x; i < BATCH * 256; i += blockDim.x)
    if (lh[i]) atomicAdd(&ws[i], lh[i]);
}

__global__ void k_scan(uint32_t* ws, int shift) {
  int tid = threadIdx.x;
  if (tid < BATCH) {
    uint32_t k = ws[514 + tid];
    uint32_t cum = 0;
    int bin = 0;
    for (int i = 255; i >= 0; --i) {
      uint32_t c = ws[tid * 256 + i];
      if (cum + c >= k) { bin = i; ws[514 + tid] = k - cum; break; }
      cum += c;
    }
    ws[512 + tid] |= ((uint32_t)bin) << shift;
  }
  __syncthreads();
  // zero histogram for next pass
  ws[tid] = 0;
  ws[256 + tid] = 0;
}

__global__ void k_compact(const float* __restrict__ s1, const float* __restrict__ s2,
                          const float* __restrict__ s3, uint32_t* ws) {
  unsigned long long* cand = (unsigned long long*)((char*)ws + 4096);
  uint32_t t0 = ws[512];
  uint32_t t1 = ws[513];
  const int total = BATCH * N_TOT;
  for (int idx = blockIdx.x * blockDim.x + threadIdx.x; idx < total;
       idx += gridDim.x * blockDim.x) {
    int b = (idx >= N_TOT) ? 1 : 0;
    int n = idx - b * N_TOT;
    uint32_t key = score_key(b, n, s1, s2, s3);
    uint32_t T = b ? t1 : t0;
    if (key >= T) {
      uint32_t pos = atomicAdd(&ws[516 + b], 1u);
      if (pos < CAND_CAP)
        cand[(unsigned)b * CAND_CAP + pos] =
            ((unsigned long long)key << 32) | (uint32_t)(~(uint32_t)n);
    }
  }
}

__global__ void __launch_bounds__(1024) k_sort(uint32_t* ws) {
  __shared__ unsigned long long sh[CAND_CAP];
  const int b = blockIdx.x;
  const int tid = threadIdx.x;
  uint32_t cnt = ws[516 + b];
  if (cnt > CAND_CAP) cnt = CAND_CAP;
  const unsigned long long* cand =
      (const unsigned long long*)((char*)ws + 4096) + (unsigned)b * CAND_CAP;
  unsigned long long* sorted =
      (unsigned long long*)((char*)ws + 36864) + (unsigned)b * TOPK;
  for (int i = tid; i < CAND_CAP; i += 1024)
    sh[i] = (i < (int)cnt) ? cand[i] : 0ULL;
  // bitonic sort, descending
  for (int k = 2; k <= CAND_CAP; k <<= 1) {
    for (int j = k >> 1; j > 0; j >>= 1) {
      __syncthreads();
      for (int i = tid; i < CAND_CAP; i += 1024) {
        int ixj = i ^ j;
        if (ixj > i) {
          unsigned long long x = sh[i], y = sh[ixj];
          bool up = ((i & k) == 0);
          bool sw = up ? (x < y) : (x > y);
          if (sw) { sh[i] = y; sh[ixj] = x; }
        }
      }
    }
  }
  __syncthreads();
  for (int i = tid; i < TOPK; i += 1024) sorted[i] = sh[i];
}

__global__ void k_emit(const float* __restrict__ b1, const float* __restrict__ b2,
                       const float* __restrict__ b3, const float* __restrict__ anchors,
                       const float* __restrict__ im_info, const uint32_t* ws,
                       float* __restrict__ out) {
  int gid = blockIdx.x * blockDim.x + threadIdx.x;
  int e = gid >> 4;
  int s = gid & 15;
  if (e >= BATCH * TOPK) return;
  int b = e / TOPK;
  int r = e - b * TOPK;
  const unsigned long long* sorted =
      (const unsigned long long*)((const char*)ws + 36864);
  unsigned long long p = sorted[(unsigned)b * TOPK + r];
  uint32_t key = (uint32_t)(p >> 32);
  uint32_t n = ~(uint32_t)p;
  uint32_t sb = (key & 0x80000000u) ? (key ^ 0x80000000u) : ~key;
  float score = __uint_as_float(sb);

  int j, a, td;
  const float* bb;
  long base;
  if ((int)n < G1_END) {
    j = 0; a = (int)n; td = 16; bb = b1;
    base = ((long)b * A_CNT + a) * 16 * 4;
  } else if ((int)n < G2_END) {
    int m = (int)n - G1_END;
    j = m / A_CNT; a = m - j * A_CNT; td = 8; bb = b2;
    base = (((long)b * 9 + j) * A_CNT + a) * 8 * 4;
  } else {
    int m = (int)n - G2_END;
    j = m / A_CNT; a = m - j * A_CNT; td = 4; bb = b3;
    base = (((long)b * 13 + j) * A_CNT + a) * 4 * 4;
  }

  float x1, y1, x2, y2;
  if (s >= j && s < j + td) {
    const float* an = anchors + (long)a * 4;
    float a0 = an[0], a1 = an[1], a2 = an[2], a3 = an[3];
    const float* d = bb + base + (long)(s - j) * 4;
    float dx = d[0], dy = d[1], dw = d[2], dh = d[3];
    float aw = a2 - a0 + 1.0f, ah = a3 - a1 + 1.0f;
    float acx = a0 + 0.5f * aw, acy = a1 + 0.5f * ah;
    float pcx = dx * aw + acx, pcy = dy * ah + acy;
    float pw = expf(dw) * aw, ph = expf(dh) * ah;
    x1 = pcx - 0.5f * pw;
    y1 = pcy - 0.5f * ph;
    x2 = pcx + 0.5f * pw;
    y2 = pcy + 0.5f * ph;
    float hmax = im_info[b * 3 + 0] - 1.0f;
    float wmax = im_info[b * 3 + 1] - 1.0f;
    x1 = fminf(fmaxf(x1, 0.0f), wmax);
    x2 = fminf(fmaxf(x2, 0.0f), wmax);
    y1 = fminf(fmaxf(y1, 0.0f), hmax);
    y2 = fminf(fmaxf(y2, 0.0f), hmax);
  } else {
    x1 = 0.0f; y1 = 0.0f; x2 = 1.0f; y2 = 1.0f;
  }
  float* o = out + (long)e * 66;
  o[1 + 4 * s] = x1;
  o[2 + 4 * s] = y1;
  o[3 + 4 * s] = x2;
  o[4 + 4 * s] = y2;
  if (s == 0) {
    o[0] = (float)b;
    o[65] = score;
  }
}

extern "C" void kernel_launch(void* const* d_in, const int* in_sizes, int n_in,
                              void* d_out, int out_size, void* d_ws, size_t ws_size,
                              hipStream_t stream) {
  const float* s1 = (const float*)d_in[0];
  const float* s2 = (const float*)d_in[1];
  const float* s3 = (const float*)d_in[2];
  const float* b1 = (const float*)d_in[3];
  const float* b2 = (const float*)d_in[4];
  const float* b3 = (const float*)d_in[5];
  const float* anchors = (const float*)d_in[6];
  const float* im_info = (const float*)d_in[7];
  uint32_t* ws = (uint32_t*)d_ws;
  float* out = (float*)d_out;

  k_init<<<1, 512, 0, stream>>>(ws);
  for (int pass = 0; pass < 4; ++pass) {
    int shift = 24 - 8 * pass;
    k_hist<<<512, 256, 0, stream>>>(s1, s2, s3, ws, shift);
    k_scan<<<1, 256, 0, stream>>>(ws, shift);
  }
  k_compact<<<512, 256, 0, stream>>>(s1, s2, s3, ws);
  k_sort<<<BATCH, 1024, 0, stream>>>(ws);
  int threads = BATCH * TOPK * 16;
  k_emit<<<(threads + 255) / 256, 256, 0, stream>>>(b1, b2, b3, anchors, im_info,
                                                    ws, out);
}

// Round 2
// 107.767 us; speedup vs baseline: 1.7628x; 1.7628x over previous
//
#include <hip/hip_runtime.h>
#include <stdint.h>

#define A_CNT 16320
#define N_TOT (23 * A_CNT)       // 375360 windowed anchors per batch
#define G1_END A_CNT             // group0: td=16, W=1
#define G2_END (10 * A_CNT)      // group1: td=8,  W=9
#define BATCH 2
#define TOPK 2000
#define NBIN 2048                // 11-bit histogram of key top bits
#define NREP 4                   // replicated global histograms
#define CANDCAP 4096
#define LCAP 256                 // per-block LDS candidate cap (per batch)
#define TOT4 375360              // total float4 loads (= BATCH*N_TOT/2)

// ws layout:
//   u32[0..1]   T[2] threshold keys
//   u32[2..3]   gCandCnt[2]
//   u32[16..]   hist replicas: NREP x [2][NBIN] u32  (4 * 16KB = 64KB)
//   byte 65600  cand[2][CANDCAP] u64
// total ~128 KB

__device__ __forceinline__ uint32_t fkey(float v) {
  uint32_t u = __float_as_uint(v);
  return (u & 0x80000000u) ? ~u : (u | 0x80000000u);
}

// g in [0, TOT4): one float4 = scores for anchors (n0, n0+1), batch b.
__device__ __forceinline__ float4 load_pair(int g, const float* __restrict__ s1,
                                            const float* __restrict__ s2,
                                            const float* __restrict__ s3,
                                            int& b, int& n0) {
  if (g < 16320) {                       // s1: [B][1][A][2]
    b = g / 8160;
    int w = g - b * 8160;
    n0 = 2 * w;
    return ((const float4*)s1)[g];
  } else if (g < 163200) {               // s2: [B][9][A][2]
    int h = g - 16320;
    b = h / 73440;
    int w = h - b * 73440;
    int j = w / 8160;
    int p = w - j * 8160;
    n0 = A_CNT + j * A_CNT + 2 * p;
    return ((const float4*)s2)[h];
  } else {                               // s3: [B][13][A][2]
    int h = g - 163200;
    b = h / 106080;
    int w = h - b * 106080;
    int j = w / 8160;
    int p = w - j * 8160;
    n0 = 10 * A_CNT + j * A_CNT + 2 * p;
    return ((const float4*)s3)[h];
  }
}

__global__ void k_hist(const float* __restrict__ s1, const float* __restrict__ s2,
                       const float* __restrict__ s3, uint32_t* ws) {
  __shared__ uint32_t lh[BATCH * NBIN];
  for (int i = threadIdx.x; i < BATCH * NBIN; i += blockDim.x) lh[i] = 0;
  __syncthreads();
  for (int g = blockIdx.x * blockDim.x + threadIdx.x; g < TOT4;
       g += gridDim.x * blockDim.x) {
    int b, n0;
    float4 v = load_pair(g, s1, s2, s3, b, n0);
    atomicAdd(&lh[b * NBIN + (fkey(v.y) >> 21)], 1u);
    atomicAdd(&lh[b * NBIN + (fkey(v.w) >> 21)], 1u);
  }
  __syncthreads();
  uint32_t* gh = ws + 16 + (blockIdx.x & (NREP - 1)) * (BATCH * NBIN);
  for (int i = threadIdx.x; i < BATCH * NBIN; i += blockDim.x)
    if (lh[i]) atomicAdd(&gh[i], lh[i]);
}

__global__ void __launch_bounds__(1024) k_scan(uint32_t* ws) {
  __shared__ uint32_t hist[NBIN];
  __shared__ uint32_t ps[1024];
  const int tid = threadIdx.x;
  for (int b = 0; b < BATCH; ++b) {
    for (int i = tid; i < NBIN; i += 1024) {
      uint32_t s = 0;
      for (int r = 0; r < NREP; ++r)
        s += ws[16 + r * (BATCH * NBIN) + b * NBIN + i];
      hist[i] = s;
    }
    __syncthreads();
    ps[tid] = hist[2 * tid] + hist[2 * tid + 1];
    __syncthreads();
    // inclusive suffix scan over the 1024 pair-sums
    for (int off = 1; off < 1024; off <<= 1) {
      uint32_t add = (tid + off < 1024) ? ps[tid + off] : 0u;
      __syncthreads();
      ps[tid] += add;
      __syncthreads();
    }
    // ps[t] = count of keys with bin >= 2t
    uint32_t cge0 = ps[tid];                       // count(bin >= 2t)
    uint32_t cge1 = ps[tid] - hist[2 * tid];       // count(bin >= 2t+1)
    uint32_t cge2 = (tid < 1023) ? ps[tid + 1] : 0u;  // count(bin >= 2t+2)
    if (cge0 >= TOPK && cge1 < TOPK) ws[b] = ((uint32_t)(2 * tid)) << 21;
    if (cge1 >= TOPK && cge2 < TOPK) ws[b] = ((uint32_t)(2 * tid + 1)) << 21;
    __syncthreads();
  }
}

__global__ void k_compact(const float* __restrict__ s1, const float* __restrict__ s2,
                          const float* __restrict__ s3, uint32_t* ws) {
  __shared__ unsigned long long buf[BATCH][LCAP];
  __shared__ uint32_t cnt[BATCH], base[BATCH];
  if (threadIdx.x < BATCH) cnt[threadIdx.x] = 0;
  __syncthreads();
  const uint32_t T0 = ws[0], T1 = ws[1];
  unsigned long long* cand = (unsigned long long*)((char*)ws + 65600);
  for (int g = blockIdx.x * blockDim.x + threadIdx.x; g < TOT4;
       g += gridDim.x * blockDim.x) {
    int b, n0;
    float4 v = load_pair(g, s1, s2, s3, b, n0);
    uint32_t T = b ? T1 : T0;
#pragma unroll
    for (int h = 0; h < 2; ++h) {
      uint32_t key = fkey(h ? v.w : v.y);
      if (key >= T) {
        uint32_t n = (uint32_t)(n0 + h);
        unsigned long long pk = ((unsigned long long)key << 32) | (uint32_t)(~n);
        uint32_t p = atomicAdd(&cnt[b], 1u);
        if (p < LCAP) {
          buf[b][p] = pk;
        } else {  // overflow fallback (statistically never taken)
          uint32_t gp = atomicAdd(&ws[2 + b], 1u);
          if (gp < CANDCAP) cand[(unsigned)b * CANDCAP + gp] = pk;
        }
      }
    }
  }
  __syncthreads();
  if (threadIdx.x < BATCH) {
    uint32_t c = cnt[threadIdx.x];
    if (c > LCAP) c = LCAP;
    base[threadIdx.x] = atomicAdd(&ws[2 + threadIdx.x], c);
  }
  __syncthreads();
  for (int b = 0; b < BATCH; ++b) {
    uint32_t c = cnt[b];
    if (c > LCAP) c = LCAP;
    for (uint32_t i = threadIdx.x; i < c; i += blockDim.x) {
      uint32_t pos = base[b] + i;
      if (pos < CANDCAP) cand[(unsigned)b * CANDCAP + pos] = buf[b][i];
    }
  }
}

__global__ void __launch_bounds__(1024) k_sortemit(
    const float* __restrict__ b1, const float* __restrict__ b2,
    const float* __restrict__ b3, const float* __restrict__ anchors,
    const float* __restrict__ im_info, uint32_t* ws, float* __restrict__ out) {
  __shared__ unsigned long long sh[CANDCAP];
  const int b = blockIdx.x;
  const int tid = threadIdx.x;
  uint32_t cnt = ws[2 + b];
  if (cnt > CANDCAP) cnt = CANDCAP;
  const unsigned long long* cand =
      (const unsigned long long*)((const char*)ws + 65600) + (unsigned)b * CANDCAP;
  for (int i = tid; i < CANDCAP; i += 1024)
    sh[i] = (i < (int)cnt) ? cand[i] : 0ULL;
  // bitonic sort descending over 4096
  for (int k = 2; k <= CANDCAP; k <<= 1) {
    for (int j = k >> 1; j > 0; j >>= 1) {
      __syncthreads();
      for (int i = tid; i < CANDCAP; i += 1024) {
        int ixj = i ^ j;
        if (ixj > i) {
          unsigned long long x = sh[i], y = sh[ixj];
          bool up = ((i & k) == 0);
          if (up ? (x < y) : (x > y)) { sh[i] = y; sh[ixj] = x; }
        }
      }
    }
  }
  __syncthreads();
  const float hmax = im_info[b * 3 + 0] - 1.0f;
  const float wmax = im_info[b * 3 + 1] - 1.0f;
  for (int w = tid; w < TOPK * 16; w += 1024) {
    int r = w >> 4, s = w & 15;
    unsigned long long p = sh[r];
    uint32_t key = (uint32_t)(p >> 32);
    uint32_t n = ~(uint32_t)p;
    int j, a, td;
    const float* bb;
    long base;
    if ((int)n < G1_END) {
      j = 0; a = (int)n; td = 16; bb = b1;
      base = ((long)b * A_CNT + a) * 64;
    } else if ((int)n < G2_END) {
      int m = (int)n - G1_END;
      j = m / A_CNT; a = m - j * A_CNT; td = 8; bb = b2;
      base = (((long)b * 9 + j) * A_CNT + a) * 32;
    } else {
      int m = (int)n - G2_END;
      j = m / A_CNT; a = m - j * A_CNT; td = 4; bb = b3;
      base = (((long)b * 13 + j) * A_CNT + a) * 16;
    }
    float x1, y1, x2, y2;
    if (s >= j && s < j + td) {
      const float* an = anchors + (long)a * 4;
      float a0 = an[0], a1 = an[1], a2 = an[2], a3 = an[3];
      const float* d = bb + base + (long)(s - j) * 4;
      float dx = d[0], dy = d[1], dw = d[2], dh = d[3];
      float aw = a2 - a0 + 1.0f, ah = a3 - a1 + 1.0f;
      float acx = a0 + 0.5f * aw, acy = a1 + 0.5f * ah;
      float pcx = dx * aw + acx, pcy = dy * ah + acy;
      float pw = expf(dw) * aw, ph = expf(dh) * ah;
      x1 = fminf(fmaxf(pcx - 0.5f * pw, 0.0f), wmax);
      y1 = fminf(fmaxf(pcy - 0.5f * ph, 0.0f), hmax);
      x2 = fminf(fmaxf(pcx + 0.5f * pw, 0.0f), wmax);
      y2 = fminf(fmaxf(pcy + 0.5f * ph, 0.0f), hmax);
    } else {
      x1 = 0.0f; y1 = 0.0f; x2 = 1.0f; y2 = 1.0f;
    }
    float* o = out + ((long)b * TOPK + r) * 66;
    o[1 + 4 * s] = x1;
    o[2 + 4 * s] = y1;
    o[3 + 4 * s] = x2;
    o[4 + 4 * s] = y2;
    if (s == 0) {
      uint32_t sb = (key & 0x80000000u) ? (key ^ 0x80000000u) : ~key;
      o[0] = (float)b;
      o[65] = __uint_as_float(sb);
    }
  }
}

extern "C" void kernel_launch(void* const* d_in, const int* in_sizes, int n_in,
                              void* d_out, int out_size, void* d_ws, size_t ws_size,
                              hipStream_t stream) {
  const float* s1 = (const float*)d_in[0];
  const float* s2 = (const float*)d_in[1];
  const float* s3 = (const float*)d_in[2];
  const float* b1 = (const float*)d_in[3];
  const float* b2 = (const float*)d_in[4];
  const float* b3 = (const float*)d_in[5];
  const float* anchors = (const float*)d_in[6];
  const float* im_info = (const float*)d_in[7];
  uint32_t* ws = (uint32_t*)d_ws;
  float* out = (float*)d_out;

  // zero: T[2], candCnt[2], pad, 4 hist replicas  (bytes 0..65600)
  hipMemsetAsync(d_ws, 0, 65600, stream);
  k_hist<<<256, 256, 0, stream>>>(s1, s2, s3, ws);
  k_scan<<<1, 1024, 0, stream>>>(ws);
  k_compact<<<256, 256, 0, stream>>>(s1, s2, s3, ws);
  k_sortemit<<<BATCH, 1024, 0, stream>>>(b1, b2, b3, anchors, im_info, ws, out);
}

// Round 3
// 64.702 us; speedup vs baseline: 2.9361x; 1.6656x over previous
//
#include <hip/hip_runtime.h>
#include <stdint.h>

#define A_CNT 16320
#define N_TOT (23 * A_CNT)       // 375360 windowed anchors per batch
#define G1_END A_CNT             // group0: td=16, W=1
#define G2_END (10 * A_CNT)      // group1: td=8,  W=9
#define BATCH 2
#define TOPK 2000
#define NBIN 2048                // 11-bit histogram of key top bits
#define NREP 4                   // replicated global histograms
#define CANDCAP 4096
#define LCAP 256                 // per-block LDS candidate cap (per batch)
#define TOT4 375360              // total float4 loads (= BATCH*N_TOT/2)

// ws layout:
//   u32[0..1]     T[2] threshold keys
//   u32[2..3]     gCandCnt[2]
//   byte 64       hist replicas: NREP x [2][NBIN] u32 (64 KB) -- dead after k_scan
//   byte 1024     ranked[2][TOPK] u64 (32 KB)  -- OVERLAPS dead hist region,
//                 written by k_rank (after k_scan), read by k_emit
//   byte 65600    cand[2][CANDCAP] u64 (64 KB)
// total ~131 KB

__device__ __forceinline__ uint32_t fkey(float v) {
  uint32_t u = __float_as_uint(v);
  return (u & 0x80000000u) ? ~u : (u | 0x80000000u);
}

// g in [0, TOT4): one float4 = scores for anchors (n0, n0+1), batch b.
__device__ __forceinline__ float4 load_pair(int g, const float* __restrict__ s1,
                                            const float* __restrict__ s2,
                                            const float* __restrict__ s3,
                                            int& b, int& n0) {
  if (g < 16320) {                       // s1: [B][1][A][2]
    b = g / 8160;
    int w = g - b * 8160;
    n0 = 2 * w;
    return ((const float4*)s1)[g];
  } else if (g < 163200) {               // s2: [B][9][A][2]
    int h = g - 16320;
    b = h / 73440;
    int w = h - b * 73440;
    int j = w / 8160;
    int p = w - j * 8160;
    n0 = A_CNT + j * A_CNT + 2 * p;
    return ((const float4*)s2)[h];
  } else {                               // s3: [B][13][A][2]
    int h = g - 163200;
    b = h / 106080;
    int w = h - b * 106080;
    int j = w / 8160;
    int p = w - j * 8160;
    n0 = 10 * A_CNT + j * A_CNT + 2 * p;
    return ((const float4*)s3)[h];
  }
}

__global__ void k_hist(const float* __restrict__ s1, const float* __restrict__ s2,
                       const float* __restrict__ s3, uint32_t* ws) {
  __shared__ uint32_t lh[BATCH * NBIN];
  for (int i = threadIdx.x; i < BATCH * NBIN; i += blockDim.x) lh[i] = 0;
  __syncthreads();
  for (int g = blockIdx.x * blockDim.x + threadIdx.x; g < TOT4;
       g += gridDim.x * blockDim.x) {
    int b, n0;
    float4 v = load_pair(g, s1, s2, s3, b, n0);
    atomicAdd(&lh[b * NBIN + (fkey(v.y) >> 21)], 1u);
    atomicAdd(&lh[b * NBIN + (fkey(v.w) >> 21)], 1u);
  }
  __syncthreads();
  uint32_t* gh = ws + 16 + (blockIdx.x & (NREP - 1)) * (BATCH * NBIN);
  for (int i = threadIdx.x; i < BATCH * NBIN; i += blockDim.x)
    if (lh[i]) atomicAdd(&gh[i], lh[i]);
}

__global__ void __launch_bounds__(1024) k_scan(uint32_t* ws) {
  __shared__ uint32_t hist[NBIN];
  __shared__ uint32_t ps[1024];
  const int tid = threadIdx.x;
  for (int b = 0; b < BATCH; ++b) {
    for (int i = tid; i < NBIN; i += 1024) {
      uint32_t s = 0;
      for (int r = 0; r < NREP; ++r)
        s += ws[16 + r * (BATCH * NBIN) + b * NBIN + i];
      hist[i] = s;
    }
    __syncthreads();
    ps[tid] = hist[2 * tid] + hist[2 * tid + 1];
    __syncthreads();
    // inclusive suffix scan over the 1024 pair-sums
    for (int off = 1; off < 1024; off <<= 1) {
      uint32_t add = (tid + off < 1024) ? ps[tid + off] : 0u;
      __syncthreads();
      ps[tid] += add;
      __syncthreads();
    }
    // ps[t] = count of keys with bin >= 2t
    uint32_t cge0 = ps[tid];                       // count(bin >= 2t)
    uint32_t cge1 = ps[tid] - hist[2 * tid];       // count(bin >= 2t+1)
    uint32_t cge2 = (tid < 1023) ? ps[tid + 1] : 0u;  // count(bin >= 2t+2)
    if (cge0 >= TOPK && cge1 < TOPK) ws[b] = ((uint32_t)(2 * tid)) << 21;
    if (cge1 >= TOPK && cge2 < TOPK) ws[b] = ((uint32_t)(2 * tid + 1)) << 21;
    __syncthreads();
  }
}

__global__ void k_compact(const float* __restrict__ s1, const float* __restrict__ s2,
                          const float* __restrict__ s3, uint32_t* ws) {
  __shared__ unsigned long long buf[BATCH][LCAP];
  __shared__ uint32_t cnt[BATCH], base[BATCH];
  if (threadIdx.x < BATCH) cnt[threadIdx.x] = 0;
  __syncthreads();
  const uint32_t T0 = ws[0], T1 = ws[1];
  unsigned long long* cand = (unsigned long long*)((char*)ws + 65600);
  for (int g = blockIdx.x * blockDim.x + threadIdx.x; g < TOT4;
       g += gridDim.x * blockDim.x) {
    int b, n0;
    float4 v = load_pair(g, s1, s2, s3, b, n0);
    uint32_t T = b ? T1 : T0;
#pragma unroll
    for (int h = 0; h < 2; ++h) {
      uint32_t key = fkey(h ? v.w : v.y);
      if (key >= T) {
        uint32_t n = (uint32_t)(n0 + h);
        unsigned long long pk = ((unsigned long long)key << 32) | (uint32_t)(~n);
        uint32_t p = atomicAdd(&cnt[b], 1u);
        if (p < LCAP) {
          buf[b][p] = pk;
        } else {  // overflow fallback (statistically never taken)
          uint32_t gp = atomicAdd(&ws[2 + b], 1u);
          if (gp < CANDCAP) cand[(unsigned)b * CANDCAP + gp] = pk;
        }
      }
    }
  }
  __syncthreads();
  if (threadIdx.x < BATCH) {
    uint32_t c = cnt[threadIdx.x];
    if (c > LCAP) c = LCAP;
    base[threadIdx.x] = atomicAdd(&ws[2 + threadIdx.x], c);
  }
  __syncthreads();
  for (int b = 0; b < BATCH; ++b) {
    uint32_t c = cnt[b];
    if (c > LCAP) c = LCAP;
    for (uint32_t i = threadIdx.x; i < c; i += blockDim.x) {
      uint32_t pos = base[b] + i;
      if (pos < CANDCAP) cand[(unsigned)b * CANDCAP + pos] = buf[b][i];
    }
  }
}

// Exact stable descending rank by brute-force count; scatter into ranked[].
__global__ void __launch_bounds__(256) k_rank(uint32_t* ws) {
  __shared__ unsigned long long tile[1024];
  const int b = blockIdx.y;
  uint32_t cnt = ws[2 + b];
  if (cnt > CANDCAP) cnt = CANDCAP;
  const unsigned long long* cand =
      (const unsigned long long*)((const char*)ws + 65600) + (unsigned)b * CANDCAP;
  unsigned long long* ranked =
      (unsigned long long*)((char*)ws + 1024) + (unsigned)b * TOPK;
  const int i = blockIdx.x * 256 + threadIdx.x;
  unsigned long long mine = (i < (int)cnt) ? cand[i] : 0ULL;
  uint32_t rank = 0;
  for (uint32_t t = 0; t < cnt; t += 1024) {
    uint32_t lim = min(1024u, cnt - t);
    __syncthreads();
    for (uint32_t j = threadIdx.x; j < lim; j += 256) tile[j] = cand[t + j];
    __syncthreads();
    if (i < (int)cnt) {
      for (uint32_t j = 0; j < lim; ++j) rank += (tile[j] > mine) ? 1u : 0u;
    }
  }
  if (i < (int)cnt && rank < TOPK) ranked[rank] = mine;
}

__global__ void k_emit(const float* __restrict__ b1, const float* __restrict__ b2,
                       const float* __restrict__ b3, const float* __restrict__ anchors,
                       const float* __restrict__ im_info, const uint32_t* ws,
                       float* __restrict__ out) {
  int gid = blockIdx.x * blockDim.x + threadIdx.x;
  int e = gid >> 4;
  int s = gid & 15;
  if (e >= BATCH * TOPK) return;
  int b = e / TOPK;
  int r = e - b * TOPK;
  const unsigned long long* ranked =
      (const unsigned long long*)((const char*)ws + 1024);
  unsigned long long p = ranked[(unsigned)b * TOPK + r];
  uint32_t key = (uint32_t)(p >> 32);
  uint32_t n = ~(uint32_t)p;

  int j, a, td;
  const float* bb;
  long base;
  if ((int)n < G1_END) {
    j = 0; a = (int)n; td = 16; bb = b1;
    base = ((long)b * A_CNT + a) * 64;
  } else if ((int)n < G2_END) {
    int m = (int)n - G1_END;
    j = m / A_CNT; a = m - j * A_CNT; td = 8; bb = b2;
    base = (((long)b * 9 + j) * A_CNT + a) * 32;
  } else {
    int m = (int)n - G2_END;
    j = m / A_CNT; a = m - j * A_CNT; td = 4; bb = b3;
    base = (((long)b * 13 + j) * A_CNT + a) * 16;
  }

  float x1, y1, x2, y2;
  if (s >= j && s < j + td) {
    const float4 an = *(const float4*)(anchors + (long)a * 4);
    const float4 d = *(const float4*)(bb + base + (long)(s - j) * 4);
    float aw = an.z - an.x + 1.0f, ah = an.w - an.y + 1.0f;
    float acx = an.x + 0.5f * aw, acy = an.y + 0.5f * ah;
    float pcx = d.x * aw + acx, pcy = d.y * ah + acy;
    float pw = expf(d.z) * aw, ph = expf(d.w) * ah;
    float hmax = im_info[b * 3 + 0] - 1.0f;
    float wmax = im_info[b * 3 + 1] - 1.0f;
    x1 = fminf(fmaxf(pcx - 0.5f * pw, 0.0f), wmax);
    y1 = fminf(fmaxf(pcy - 0.5f * ph, 0.0f), hmax);
    x2 = fminf(fmaxf(pcx + 0.5f * pw, 0.0f), wmax);
    y2 = fminf(fmaxf(pcy + 0.5f * ph, 0.0f), hmax);
  } else {
    x1 = 0.0f; y1 = 0.0f; x2 = 1.0f; y2 = 1.0f;
  }
  float* o = out + (long)e * 66;
  o[1 + 4 * s] = x1;
  o[2 + 4 * s] = y1;
  o[3 + 4 * s] = x2;
  o[4 + 4 * s] = y2;
  if (s == 0) {
    uint32_t sb = (key & 0x80000000u) ? (key ^ 0x80000000u) : ~key;
    o[0] = (float)b;
    o[65] = __uint_as_float(sb);
  }
}

extern "C" void kernel_launch(void* const* d_in, const int* in_sizes, int n_in,
                              void* d_out, int out_size, void* d_ws, size_t ws_size,
                              hipStream_t stream) {
  const float* s1 = (const float*)d_in[0];
  const float* s2 = (const float*)d_in[1];
  const float* s3 = (const float*)d_in[2];
  const float* b1 = (const float*)d_in[3];
  const float* b2 = (const float*)d_in[4];
  const float* b3 = (const float*)d_in[5];
  const float* anchors = (const float*)d_in[6];
  const float* im_info = (const float*)d_in[7];
  uint32_t* ws = (uint32_t*)d_ws;
  float* out = (float*)d_out;

  // zero: T[2], candCnt[2], hist replicas (ranked[] overlap included)
  hipMemsetAsync(d_ws, 0, 65600, stream);
  k_hist<<<256, 256, 0, stream>>>(s1, s2, s3, ws);
  k_scan<<<1, 1024, 0, stream>>>(ws);
  k_compact<<<256, 256, 0, stream>>>(s1, s2, s3, ws);
  dim3 rgrid(CANDCAP / 256, BATCH);
  k_rank<<<rgrid, 256, 0, stream>>>(ws);
  int threads = BATCH * TOPK * 16;
  k_emit<<<(threads + 255) / 256, 256, 0, stream>>>(b1, b2, b3, anchors, im_info,
                                                    ws, out);
}

// Round 4
// 64.087 us; speedup vs baseline: 2.9642x; 1.0096x over previous
//
#include <hip/hip_runtime.h>
#include <stdint.h>

#define A_CNT 16320
#define N_TOT (23 * A_CNT)       // 375360 windowed anchors per batch
#define G1_END A_CNT             // group0: td=16, W=1
#define G2_END (10 * A_CNT)      // group1: td=8,  W=9
#define BATCH 2
#define TOPK 2000
#define NBIN 2048                // 11-bit histogram of key top bits
#define NREP 4                   // replicated global histograms
#define CANDCAP 4096
#define LCAP 256                 // per-block LDS candidate cap (per batch)
#define TOT4 375360              // total float4 loads (= BATCH*N_TOT/2)
#define INIT_U4 4100             // 65600 bytes / 16

// ws layout:
//   u32[0..1]     T[2] threshold keys
//   u32[2..3]     gCandCnt[2]
//   byte 64       hist replicas: NREP x [2][NBIN] u32 (64 KB) -- dead after k_scan
//   byte 1024     ranked[2][TOPK] u64 (32 KB)  -- OVERLAPS dead hist region,
//                 written by k_rank (after k_scan), read by k_emit
//   byte 65600    cand[2][CANDCAP] u64 (64 KB)
// total ~131 KB

__device__ __forceinline__ uint32_t fkey(float v) {
  uint32_t u = __float_as_uint(v);
  return (u & 0x80000000u) ? ~u : (u | 0x80000000u);
}

__global__ void k_init(uint4* ws4) {
  int g = blockIdx.x * blockDim.x + threadIdx.x;
  if (g < INIT_U4) ws4[g] = make_uint4(0u, 0u, 0u, 0u);
}

// g in [0, TOT4): one float4 = scores for anchors (n0, n0+1), batch b.
__device__ __forceinline__ float4 load_pair(int g, const float* __restrict__ s1,
                                            const float* __restrict__ s2,
                                            const float* __restrict__ s3,
                                            int& b, int& n0) {
  if (g < 16320) {                       // s1: [B][1][A][2]
    b = g / 8160;
    int w = g - b * 8160;
    n0 = 2 * w;
    return ((const float4*)s1)[g];
  } else if (g < 163200) {               // s2: [B][9][A][2]
    int h = g - 16320;
    b = h / 73440;
    int w = h - b * 73440;
    int j = w / 8160;
    int p = w - j * 8160;
    n0 = A_CNT + j * A_CNT + 2 * p;
    return ((const float4*)s2)[h];
  } else {                               // s3: [B][13][A][2]
    int h = g - 163200;
    b = h / 106080;
    int w = h - b * 106080;
    int j = w / 8160;
    int p = w - j * 8160;
    n0 = 10 * A_CNT + j * A_CNT + 2 * p;
    return ((const float4*)s3)[h];
  }
}

__global__ void k_hist(const float* __restrict__ s1, const float* __restrict__ s2,
                       const float* __restrict__ s3, uint32_t* ws) {
  __shared__ uint32_t lh[BATCH * NBIN];
  for (int i = threadIdx.x; i < BATCH * NBIN; i += blockDim.x) lh[i] = 0;
  __syncthreads();
  for (int g = blockIdx.x * blockDim.x + threadIdx.x; g < TOT4;
       g += gridDim.x * blockDim.x) {
    int b, n0;
    float4 v = load_pair(g, s1, s2, s3, b, n0);
    atomicAdd(&lh[b * NBIN + (fkey(v.y) >> 21)], 1u);
    atomicAdd(&lh[b * NBIN + (fkey(v.w) >> 21)], 1u);
  }
  __syncthreads();
  uint32_t* gh = ws + 16 + (blockIdx.x & (NREP - 1)) * (BATCH * NBIN);
  for (int i = threadIdx.x; i < BATCH * NBIN; i += blockDim.x)
    if (lh[i]) atomicAdd(&gh[i], lh[i]);
}

__global__ void __launch_bounds__(1024) k_scan(uint32_t* ws) {
  __shared__ uint32_t hist[NBIN];
  __shared__ uint32_t ps[1024];
  const int tid = threadIdx.x;
  for (int b = 0; b < BATCH; ++b) {
    for (int i = tid; i < NBIN; i += 1024) {
      uint32_t s = 0;
      for (int r = 0; r < NREP; ++r)
        s += ws[16 + r * (BATCH * NBIN) + b * NBIN + i];
      hist[i] = s;
    }
    __syncthreads();
    ps[tid] = hist[2 * tid] + hist[2 * tid + 1];
    __syncthreads();
    // inclusive suffix scan over the 1024 pair-sums
    for (int off = 1; off < 1024; off <<= 1) {
      uint32_t add = (tid + off < 1024) ? ps[tid + off] : 0u;
      __syncthreads();
      ps[tid] += add;
      __syncthreads();
    }
    // ps[t] = count of keys with bin >= 2t
    uint32_t cge0 = ps[tid];                       // count(bin >= 2t)
    uint32_t cge1 = ps[tid] - hist[2 * tid];       // count(bin >= 2t+1)
    uint32_t cge2 = (tid < 1023) ? ps[tid + 1] : 0u;  // count(bin >= 2t+2)
    if (cge0 >= TOPK && cge1 < TOPK) ws[b] = ((uint32_t)(2 * tid)) << 21;
    if (cge1 >= TOPK && cge2 < TOPK) ws[b] = ((uint32_t)(2 * tid + 1)) << 21;
    __syncthreads();
  }
}

__global__ void k_compact(const float* __restrict__ s1, const float* __restrict__ s2,
                          const float* __restrict__ s3, uint32_t* ws) {
  __shared__ unsigned long long buf[BATCH][LCAP];
  __shared__ uint32_t cnt[BATCH], base[BATCH];
  if (threadIdx.x < BATCH) cnt[threadIdx.x] = 0;
  __syncthreads();
  const uint32_t T0 = ws[0], T1 = ws[1];
  unsigned long long* cand = (unsigned long long*)((char*)ws + 65600);
  for (int g = blockIdx.x * blockDim.x + threadIdx.x; g < TOT4;
       g += gridDim.x * blockDim.x) {
    int b, n0;
    float4 v = load_pair(g, s1, s2, s3, b, n0);
    uint32_t T = b ? T1 : T0;
#pragma unroll
    for (int h = 0; h < 2; ++h) {
      uint32_t key = fkey(h ? v.w : v.y);
      if (key >= T) {
        uint32_t n = (uint32_t)(n0 + h);
        unsigned long long pk = ((unsigned long long)key << 32) | (uint32_t)(~n);
        uint32_t p = atomicAdd(&cnt[b], 1u);
        if (p < LCAP) {
          buf[b][p] = pk;
        } else {  // overflow fallback (statistically never taken)
          uint32_t gp = atomicAdd(&ws[2 + b], 1u);
          if (gp < CANDCAP) cand[(unsigned)b * CANDCAP + gp] = pk;
        }
      }
    }
  }
  __syncthreads();
  if (threadIdx.x < BATCH) {
    uint32_t c = cnt[threadIdx.x];
    if (c > LCAP) c = LCAP;
    base[threadIdx.x] = atomicAdd(&ws[2 + threadIdx.x], c);
  }
  __syncthreads();
  for (int b = 0; b < BATCH; ++b) {
    uint32_t c = cnt[b];
    if (c > LCAP) c = LCAP;
    for (uint32_t i = threadIdx.x; i < c; i += blockDim.x) {
      uint32_t pos = base[b] + i;
      if (pos < CANDCAP) cand[(unsigned)b * CANDCAP + pos] = buf[b][i];
    }
  }
}

// Exact stable descending rank by brute-force count; scatter into ranked[].
__global__ void __launch_bounds__(256) k_rank(uint32_t* ws) {
  __shared__ unsigned long long tile[1024];
  const int b = blockIdx.y;
  uint32_t cnt = ws[2 + b];
  if (cnt > CANDCAP) cnt = CANDCAP;
  const unsigned long long* cand =
      (const unsigned long long*)((const char*)ws + 65600) + (unsigned)b * CANDCAP;
  unsigned long long* ranked =
      (unsigned long long*)((char*)ws + 1024) + (unsigned)b * TOPK;
  const int i = blockIdx.x * 256 + threadIdx.x;
  unsigned long long mine = (i < (int)cnt) ? cand[i] : 0ULL;
  uint32_t rank = 0;
  for (uint32_t t = 0; t < cnt; t += 1024) {
    uint32_t lim = min(1024u, cnt - t);
    __syncthreads();
    for (uint32_t j = threadIdx.x; j < lim; j += 256) tile[j] = cand[t + j];
    __syncthreads();
    if (i < (int)cnt) {
      for (uint32_t j = 0; j < lim; ++j) rank += (tile[j] > mine) ? 1u : 0u;
    }
  }
  if (i < (int)cnt && rank < TOPK) ranked[rank] = mine;
}

__global__ void k_emit(const float* __restrict__ b1, const float* __restrict__ b2,
                       const float* __restrict__ b3, const float* __restrict__ anchors,
                       const float* __restrict__ im_info, const uint32_t* ws,
                       float* __restrict__ out) {
  int gid = blockIdx.x * blockDim.x + threadIdx.x;
  int e = gid >> 4;
  int s = gid & 15;
  if (e >= BATCH * TOPK) return;
  int b = e / TOPK;
  int r = e - b * TOPK;
  const unsigned long long* ranked =
      (const unsigned long long*)((const char*)ws + 1024);
  unsigned long long p = ranked[(unsigned)b * TOPK + r];
  uint32_t key = (uint32_t)(p >> 32);
  uint32_t n = ~(uint32_t)p;

  int j, a, td;
  const float* bb;
  long base;
  if ((int)n < G1_END) {
    j = 0; a = (int)n; td = 16; bb = b1;
    base = ((long)b * A_CNT + a) * 64;
  } else if ((int)n < G2_END) {
    int m = (int)n - G1_END;
    j = m / A_CNT; a = m - j * A_CNT; td = 8; bb = b2;
    base = (((long)b * 9 + j) * A_CNT + a) * 32;
  } else {
    int m = (int)n - G2_END;
    j = m / A_CNT; a = m - j * A_CNT; td = 4; bb = b3;
    base = (((long)b * 13 + j) * A_CNT + a) * 16;
  }

  float x1, y1, x2, y2;
  if (s >= j && s < j + td) {
    const float4 an = *(const float4*)(anchors + (long)a * 4);
    const float4 d = *(const float4*)(bb + base + (long)(s - j) * 4);
    float aw = an.z - an.x + 1.0f, ah = an.w - an.y + 1.0f;
    float acx = an.x + 0.5f * aw, acy = an.y + 0.5f * ah;
    float pcx = d.x * aw + acx, pcy = d.y * ah + acy;
    float pw = expf(d.z) * aw, ph = expf(d.w) * ah;
    float hmax = im_info[b * 3 + 0] - 1.0f;
    float wmax = im_info[b * 3 + 1] - 1.0f;
    x1 = fminf(fmaxf(pcx - 0.5f * pw, 0.0f), wmax);
    y1 = fminf(fmaxf(pcy - 0.5f * ph, 0.0f), hmax);
    x2 = fminf(fmaxf(pcx + 0.5f * pw, 0.0f), wmax);
    y2 = fminf(fmaxf(pcy + 0.5f * ph, 0.0f), hmax);
  } else {
    x1 = 0.0f; y1 = 0.0f; x2 = 1.0f; y2 = 1.0f;
  }
  float* o = out + (long)e * 66;
  o[1 + 4 * s] = x1;
  o[2 + 4 * s] = y1;
  o[3 + 4 * s] = x2;
  o[4 + 4 * s] = y2;
  if (s == 0) {
    uint32_t sb = (key & 0x80000000u) ? (key ^ 0x80000000u) : ~key;
    o[0] = (float)b;
    o[65] = __uint_as_float(sb);
  }
}

extern "C" void kernel_launch(void* const* d_in, const int* in_sizes, int n_in,
                              void* d_out, int out_size, void* d_ws, size_t ws_size,
                              hipStream_t stream) {
  const float* s1 = (const float*)d_in[0];
  const float* s2 = (const float*)d_in[1];
  const float* s3 = (const float*)d_in[2];
  const float* b1 = (const float*)d_in[3];
  const float* b2 = (const float*)d_in[4];
  const float* b3 = (const float*)d_in[5];
  const float* anchors = (const float*)d_in[6];
  const float* im_info = (const float*)d_in[7];
  uint32_t* ws = (uint32_t*)d_ws;
  float* out = (float*)d_out;

  // zero: T[2], candCnt[2], hist replicas (ranked[] overlap included)
  k_init<<<(INIT_U4 + 255) / 256, 256, 0, stream>>>((uint4*)d_ws);
  k_hist<<<256, 256, 0, stream>>>(s1, s2, s3, ws);
  k_scan<<<1, 1024, 0, stream>>>(ws);
  k_compact<<<256, 256, 0, stream>>>(s1, s2, s3, ws);
  dim3 rgrid(CANDCAP / 256, BATCH);
  k_rank<<<rgrid, 256, 0, stream>>>(ws);
  int threads = BATCH * TOPK * 16;
  k_emit<<<(threads + 255) / 256, 256, 0, stream>>>(b1, b2, b3, anchors, im_info,
                                                    ws, out);
}